// Round 1
// baseline (6564.764 us; speedup 1.0000x reference)
//
#include <hip/hip_runtime.h>
#include <stdint.h>

#define NG 4    // batch groups
#define MB 16   // batch per group
#define GW 16   // workgroups per group
#define NU 32   // hidden units per WG
#define HD 512
#define SEQ 512
#define DX 40

using short8 = __attribute__((ext_vector_type(8))) short;
using f32x4  = __attribute__((ext_vector_type(4))) float;

__device__ __forceinline__ unsigned short f2bf(float f) {
  uint32_t u = __builtin_bit_cast(uint32_t, f);
  u += 0x7fffu + ((u >> 16) & 1u);
  return (unsigned short)(u >> 16);
}
__device__ __forceinline__ float bf2f(unsigned short s) {
  uint32_t u = ((uint32_t)s) << 16;
  return __builtin_bit_cast(float, u);
}
__device__ __forceinline__ float sigm(float x) { return 1.0f / (1.0f + __expf(-x)); }

// ---------------- GRU persistent kernel ----------------
// grid = 64 blocks (4 groups x 16 WGs), 512 threads.
// Waves 0..5: MFMA over N-tiles (r,z,n x 2 unit-tiles). Waves 6,7: xn (K=40, separate
// because n = tanh(xn + r*hn)). x is folded into K for r,z (cols 512..551).
__global__ __launch_bounds__(512) void gru_kernel(
    const float* __restrict__ x, const float* __restrict__ Wih,
    const float* __restrict__ Whh, const float* __restrict__ bih,
    const float* __restrict__ bhh, unsigned* __restrict__ bar,
    unsigned short* __restrict__ hbuf, float* __restrict__ o1,
    float* __restrict__ stats)
{
  const int wg = blockIdx.x & (GW - 1);
  const int g  = blockIdx.x >> 4;
  const int tid = threadIdx.x;
  const int wave = tid >> 6;
  const int lane = tid & 63;
  const int u0 = wg * NU;
  const int bg = g * MB;

  __shared__ unsigned short h_s[MB][584];  // 512 h + 40 x + zeros, pad to 584
  __shared__ float gate_s[3][MB][NU];
  __shared__ float xn_s[MB][NU];
  __shared__ float wn_s[DX][NU];           // Wih n-gate slice, transposed

  for (int i = tid; i < DX * NU; i += 512) {
    int c = i >> 5, u = i & 31;
    wn_s[c][u] = Wih[(size_t)(2 * HD + u0 + u) * DX + c];
  }

  // Preload B-fragments (weights) into registers, bf16. B[k][n]: n=lane&15, k=quad*8+j.
  short8 bfrag[18];
  int myGate = 0;
  if (wave < 6) {
    myGate = wave >> 1;
    const int ut = wave & 1;
    const int row = myGate * HD + u0 + ut * 16 + (lane & 15);
    const int kq = (lane >> 4) * 8;
    for (int kt = 0; kt < 16; ++kt) {
      const float* p = Whh + (size_t)row * HD + kt * 32 + kq;
      short8 f;
#pragma unroll
      for (int j = 0; j < 8; ++j) f[j] = (short)f2bf(p[j]);
      bfrag[kt] = f;
    }
    for (int kt = 16; kt < 18; ++kt) {  // x part: r,z only; n-gate rows are zero
      short8 f;
#pragma unroll
      for (int j = 0; j < 8; ++j) {
        int c = kt * 32 + kq + j - HD;
        float v = (myGate < 2 && c < DX) ? Wih[(size_t)row * DX + c] : 0.0f;
        f[j] = (short)f2bf(v);
      }
      bfrag[kt] = f;
    }
  }

  // per-thread owned state (batch sb, unit su)
  const int sb = tid >> 5;
  const int su = tid & 31;
  float hprev = 0.0f, ssum = 0.0f, ssq = 0.0f;
  const float b_r  = bih[u0 + su] + bhh[u0 + su];
  const float b_z  = bih[HD + u0 + su] + bhh[HD + u0 + su];
  const float b_in = bih[2 * HD + u0 + su];
  const float b_hn = bhh[2 * HD + u0 + su];

  unsigned short* hb0 = hbuf + (size_t)g * 2 * MB * HD;  // double-buffered exchange
  unsigned* mybar = bar + g * 16;                        // 64B-strided counters

  for (int t = 0; t < SEQ; ++t) {
    const unsigned short* hin = hb0 + (t & 1) * MB * HD;
    unsigned short* hout      = hb0 + ((t + 1) & 1) * MB * HD;
    {  // stage h (16KB bf16), coalesced 16B per thread x2
      int b = tid >> 6, c = (tid & 63) * 8;
      *(uint4*)(&h_s[b][c]) = *(const uint4*)(hin + b * HD + c);
      int i1 = tid + 512;
      b = i1 >> 6; c = (i1 & 63) * 8;
      *(uint4*)(&h_s[b][c]) = *(const uint4*)(hin + b * HD + c);
    }
    {  // stage x_t into cols 512..551, zero 552..575
      int b = tid >> 5, c = tid & 31;
      const float* xr = x + ((size_t)(bg + b) * SEQ + t) * DX;
      h_s[b][HD + c] = f2bf(xr[c]);
      if (c < 8)  h_s[b][HD + 32 + c] = f2bf(xr[32 + c]);
      if (c < 24) h_s[b][552 + c] = 0;
    }
    __syncthreads();

    if (wave < 6) {
      f32x4 acc = {0.f, 0.f, 0.f, 0.f};
      const int m = lane & 15;
      const int kq = (lane >> 4) * 8;
#pragma unroll
      for (int kt = 0; kt < 18; ++kt) {
        short8 a = *(const short8*)(&h_s[m][kt * 32 + kq]);
        acc = __builtin_amdgcn_mfma_f32_16x16x32_bf16(a, bfrag[kt], acc, 0, 0, 0);
      }
      const int ut = wave & 1;
#pragma unroll
      for (int r = 0; r < 4; ++r)  // C/D: col=lane&15, row=(lane>>4)*4+reg
        gate_s[myGate][(lane >> 4) * 4 + r][ut * 16 + (lane & 15)] = acc[r];
    } else {
      int base = (tid - 384) * 4;
#pragma unroll
      for (int i = 0; i < 4; ++i) {
        int idx = base + i;
        int b = idx >> 5, u = idx & 31;
        float s = 0.0f;
        for (int c = 0; c < DX; ++c)
          s += bf2f(h_s[b][HD + c]) * wn_s[c][u];
        xn_s[b][u] = s;
      }
    }
    __syncthreads();

    {  // gate combine + state update (fp32 state in register)
      float r = sigm(gate_s[0][sb][su] + b_r);
      float z = sigm(gate_s[1][sb][su] + b_z);
      float n = tanhf(xn_s[sb][su] + b_in + r * (gate_s[2][sb][su] + b_hn));
      float h = (1.0f - z) * n + z * hprev;
      hprev = h;
      ssum += h; ssq += h * h;
      hout[sb * HD + u0 + su] = f2bf(h);
      o1[((size_t)(bg + sb) * SEQ + t) * HD + u0 + su] = h;
    }
    __syncthreads();
    if (tid == 0) {  // group barrier: monotonic counter, agent-scope
      __threadfence();
      atomicAdd(mybar, 1u);
      const unsigned target = (unsigned)(GW * (t + 1));
      while (__hip_atomic_load(mybar, __ATOMIC_RELAXED, __HIP_MEMORY_SCOPE_AGENT) < target)
        __builtin_amdgcn_s_sleep(1);
      __threadfence();
    }
    __syncthreads();
  }

  atomicAdd(&stats[u0 + su], ssum);
  atomicAdd(&stats[HD + u0 + su], ssq);
}

// ---------------- LSTM persistent kernel ----------------
// 8 MFMA waves (i,f,g,o x 2 unit-tiles); x and ssr fully folded into K (cols 512..552).
__global__ __launch_bounds__(512) void lstm_kernel(
    const float* __restrict__ x, const float* __restrict__ Wih,
    const float* __restrict__ Whh, const float* __restrict__ bih,
    const float* __restrict__ bhh, const float* __restrict__ ssr,
    unsigned* __restrict__ bar, unsigned short* __restrict__ hbuf,
    float* __restrict__ o2)
{
  const int wg = blockIdx.x & (GW - 1);
  const int g  = blockIdx.x >> 4;
  const int tid = threadIdx.x;
  const int wave = tid >> 6;
  const int lane = tid & 63;
  const int u0 = wg * NU;
  const int bg = g * MB;

  __shared__ unsigned short h_s[MB][584];
  __shared__ float gate_s[4][MB][NU];

  short8 bfrag[18];
  const int myGate = wave >> 1;
  {
    const int ut = wave & 1;
    const int row = myGate * HD + u0 + ut * 16 + (lane & 15);
    const int kq = (lane >> 4) * 8;
    for (int kt = 0; kt < 16; ++kt) {
      const float* p = Whh + (size_t)row * HD + kt * 32 + kq;
      short8 f;
#pragma unroll
      for (int j = 0; j < 8; ++j) f[j] = (short)f2bf(p[j]);
      bfrag[kt] = f;
    }
    for (int kt = 16; kt < 18; ++kt) {  // x2 = [x(40), ssr(1)] -> Wih has 41 cols
      short8 f;
#pragma unroll
      for (int j = 0; j < 8; ++j) {
        int c = kt * 32 + kq + j - HD;
        float v = (c < 41) ? Wih[(size_t)row * 41 + c] : 0.0f;
        f[j] = (short)f2bf(v);
      }
      bfrag[kt] = f;
    }
  }

  const int sb = tid >> 5;
  const int su = tid & 31;
  float creg = 0.0f;
  const float b_i = bih[u0 + su] + bhh[u0 + su];
  const float b_f = bih[HD + u0 + su] + bhh[HD + u0 + su];
  const float b_g = bih[2 * HD + u0 + su] + bhh[2 * HD + u0 + su];
  const float b_o = bih[3 * HD + u0 + su] + bhh[3 * HD + u0 + su];

  unsigned short* hb0 = hbuf + (size_t)g * 2 * MB * HD;
  unsigned* mybar = bar + g * 16;

  for (int t = 0; t < SEQ; ++t) {
    const unsigned short* hin = hb0 + (t & 1) * MB * HD;
    unsigned short* hout      = hb0 + ((t + 1) & 1) * MB * HD;
    {
      int b = tid >> 6, c = (tid & 63) * 8;
      *(uint4*)(&h_s[b][c]) = *(const uint4*)(hin + b * HD + c);
      int i1 = tid + 512;
      b = i1 >> 6; c = (i1 & 63) * 8;
      *(uint4*)(&h_s[b][c]) = *(const uint4*)(hin + b * HD + c);
    }
    {
      int b = tid >> 5, c = tid & 31;
      const float* xr = x + ((size_t)(bg + b) * SEQ + t) * DX;
      h_s[b][HD + c] = f2bf(xr[c]);
      if (c < 8)  h_s[b][HD + 32 + c] = f2bf(xr[32 + c]);
      if (c < 24) h_s[b][552 + c] =
          (c == 0) ? f2bf(ssr[(size_t)(bg + b) * SEQ + t]) : (unsigned short)0;
    }
    __syncthreads();

    {
      f32x4 acc = {0.f, 0.f, 0.f, 0.f};
      const int m = lane & 15;
      const int kq = (lane >> 4) * 8;
#pragma unroll
      for (int kt = 0; kt < 18; ++kt) {
        short8 a = *(const short8*)(&h_s[m][kt * 32 + kq]);
        acc = __builtin_amdgcn_mfma_f32_16x16x32_bf16(a, bfrag[kt], acc, 0, 0, 0);
      }
      const int ut = wave & 1;
#pragma unroll
      for (int r = 0; r < 4; ++r)
        gate_s[myGate][(lane >> 4) * 4 + r][ut * 16 + (lane & 15)] = acc[r];
    }
    __syncthreads();

    {
      float gi = sigm(gate_s[0][sb][su] + b_i);
      float gf = sigm(gate_s[1][sb][su] + b_f);
      float gg = tanhf(gate_s[2][sb][su] + b_g);
      float go = sigm(gate_s[3][sb][su] + b_o);
      creg = gf * creg + gi * gg;
      float h = go * tanhf(creg);
      hout[sb * HD + u0 + su] = f2bf(h);
      o2[((size_t)(bg + sb) * SEQ + t) * HD + u0 + su] = h;
    }
    __syncthreads();
    if (tid == 0) {
      __threadfence();
      atomicAdd(mybar, 1u);
      const unsigned target = (unsigned)(GW * (t + 1));
      while (__hip_atomic_load(mybar, __ATOMIC_RELAXED, __HIP_MEMORY_SCOPE_AGENT) < target)
        __builtin_amdgcn_s_sleep(1);
      __threadfence();
    }
    __syncthreads();
  }
}

// ---------------- BN-coefficient kernel (1 block) ----------------
// Folds BN affine into fc1/fc2: w' = fc_w*scale, c = sum(fc_w*shift) + fc_b.
__global__ __launch_bounds__(512) void coef_kernel(
    const float* __restrict__ stats, const float* __restrict__ fc1_w,
    const float* __restrict__ fc1_b, const float* __restrict__ fc2_w,
    const float* __restrict__ fc2_b, const float* __restrict__ gamma,
    const float* __restrict__ beta, float* __restrict__ coef)
{
  __shared__ float r1[512], r2[512];
  const int j = threadIdx.x;
  const float inv_n = 1.0f / 32768.0f;
  float mean = stats[j] * inv_n;
  float var = stats[HD + j] * inv_n - mean * mean;
  float scale = gamma[j] * rsqrtf(var + 1e-5f);
  float shift = beta[j] - mean * scale;
  coef[j] = fc1_w[j] * scale;
  coef[HD + j] = fc2_w[j] * scale;
  r1[j] = fc1_w[j] * shift;
  r2[j] = fc2_w[j] * shift;
  __syncthreads();
  for (int s = 256; s > 0; s >>= 1) {
    if (j < s) { r1[j] += r1[j + s]; r2[j] += r2[j + s]; }
    __syncthreads();
  }
  if (j == 0) {
    coef[2 * HD] = r1[0] + fc1_b[0];
    coef[2 * HD + 1] = r2[0] + fc2_b[0];
  }
}

// ---------------- ssr kernel: one wave per (b,t) row ----------------
__global__ __launch_bounds__(256) void ssr_kernel(
    const float* __restrict__ o1, const float* __restrict__ coef,
    float* __restrict__ ssr_ws, float* __restrict__ dssr)
{
  const int row = blockIdx.x * 4 + (threadIdx.x >> 6);
  const int lane = threadIdx.x & 63;
  const float* p = o1 + (size_t)row * HD + lane * 8;
  float s1 = 0.f, s2 = 0.f;
#pragma unroll
  for (int j = 0; j < 8; ++j) {
    float v = p[j];
    s1 += v * coef[lane * 8 + j];
    s2 += v * coef[HD + lane * 8 + j];
  }
#pragma unroll
  for (int off = 32; off > 0; off >>= 1) {
    s1 += __shfl_down(s1, off);
    s2 += __shfl_down(s2, off);
  }
  if (lane == 0) {
    float sr = fmaxf(s1 + coef[2 * HD], 0.0f);
    float w = fabsf(sigm(s2 + coef[2 * HD + 1]));
    float v = sr * (1.0f + w);
    ssr_ws[row] = v;
    dssr[row] = v;
  }
}

// ---------------- fc3 output kernel ----------------
__global__ __launch_bounds__(256) void out_kernel(
    const float* __restrict__ o2, const float* __restrict__ fc3_w,
    const float* __restrict__ fc3_b, float* __restrict__ dout)
{
  const int row = blockIdx.x * 4 + (threadIdx.x >> 6);
  const int lane = threadIdx.x & 63;
  const float* p = o2 + (size_t)row * HD + lane * 8;
  float s = 0.f;
#pragma unroll
  for (int j = 0; j < 8; ++j) s += p[j] * fc3_w[lane * 8 + j];
#pragma unroll
  for (int off = 32; off > 0; off >>= 1) s += __shfl_down(s, off);
  if (lane == 0) dout[row] = fmaxf(s + fc3_b[0], 0.0f);
}

extern "C" void kernel_launch(void* const* d_in, const int* in_sizes, int n_in,
                              void* d_out, int out_size, void* d_ws, size_t ws_size,
                              hipStream_t stream) {
  (void)in_sizes; (void)n_in; (void)out_size; (void)ws_size;
  const float* x    = (const float*)d_in[0];
  const float* gWih = (const float*)d_in[1];
  const float* gWhh = (const float*)d_in[2];
  const float* gbih = (const float*)d_in[3];
  const float* gbhh = (const float*)d_in[4];
  const float* lWih = (const float*)d_in[5];
  const float* lWhh = (const float*)d_in[6];
  const float* lbih = (const float*)d_in[7];
  const float* lbhh = (const float*)d_in[8];
  const float* fc1w = (const float*)d_in[9];
  const float* fc1b = (const float*)d_in[10];
  const float* fc2w = (const float*)d_in[11];
  const float* fc2b = (const float*)d_in[12];
  const float* fc3w = (const float*)d_in[13];
  const float* fc3b = (const float*)d_in[14];
  const float* gam  = (const float*)d_in[15];
  const float* bet  = (const float*)d_in[16];
  float* out = (float*)d_out;

  char* ws = (char*)d_ws;
  unsigned* bar_g = (unsigned*)(ws + 0);            // 4 counters, 64B stride
  unsigned* bar_l = (unsigned*)(ws + 256);
  float* stats    = (float*)(ws + 1024);            // 1024 f32
  float* coef     = (float*)(ws + 8192);            // 1026 f32
  float* ssr_ws   = (float*)(ws + 16384);           // 32768 f32
  unsigned short* hbuf_g = (unsigned short*)(ws + 147456);   // 128KB
  unsigned short* hbuf_l = (unsigned short*)(ws + 278528);   // 128KB
  float* o1 = (float*)(ws + 409600);                // 64MB
  float* o2 = o1 + (size_t)64 * SEQ * HD;           // 64MB

  // re-init every launch (ws is re-poisoned before each timed run)
  hipMemsetAsync(ws, 0, 5120, stream);              // barriers + stats
  hipMemsetAsync(ws + 147456, 0, 262144, stream);   // both h exchange buffers (h0 = 0)

  gru_kernel<<<dim3(64), dim3(512), 0, stream>>>(x, gWih, gWhh, gbih, gbhh,
                                                 bar_g, hbuf_g, o1, stats);
  coef_kernel<<<dim3(1), dim3(512), 0, stream>>>(stats, fc1w, fc1b, fc2w, fc2b,
                                                 gam, bet, coef);
  ssr_kernel<<<dim3(8192), dim3(256), 0, stream>>>(o1, coef, ssr_ws, out + 32768);
  lstm_kernel<<<dim3(64), dim3(512), 0, stream>>>(x, lWih, lWhh, lbih, lbhh, ssr_ws,
                                                  bar_l, hbuf_l, o2);
  out_kernel<<<dim3(8192), dim3(256), 0, stream>>>(o2, fc3w, fc3b, out);
}